// Round 10
// baseline (203.541 us; speedup 1.0000x reference)
//
#include <hip/hip_runtime.h>
#include <hip/hip_bf16.h>
#include <stdint.h>

// B=8, N=1024, D=1024.  out = relu(adj @ (y@W) / adj_sumrow + b + x)
// R13: R8/R11 geometry (256x128xBK64, 512thr 8 waves 4Mx2N, 256-block grids,
// XCD maps, mod-8 swizzle, grid-strided prep) with the K-loop replaced by the
// m201-style FINE phase unit (the one untried lever; R7/R9 were coarse splits
// which m196 measures as null): per K-tile 2 phases, each =
//   {3 stage-issues(T+2) ; 12 ds_read_b128 ; bar ; setprio 16-MFMA ; bar}
// counted vmcnt(6) once per tile (T+2's 6 loads always in flight), triple
// buffer (144KB), no register carry across phases (VGPR ~100, no spill).

typedef float  f32x4  __attribute__((ext_vector_type(4)));
typedef __bf16 bf16x8 __attribute__((ext_vector_type(8)));

__device__ __forceinline__ unsigned short f2bf(float f) {
  union { float f; unsigned int u; } c; c.f = f;
  unsigned int u = c.u;
  u += 0x7FFFu + ((u >> 16) & 1u);   // RNE; inputs finite
  return (unsigned short)(u >> 16);
}

__device__ __forceinline__ void async_cp16(const void* g, void* l) {
  __builtin_amdgcn_global_load_lds(
      (const __attribute__((address_space(1))) unsigned int*)g,
      (__attribute__((address_space(3))) unsigned int*)l, 16, 0, 0);
}

__device__ __forceinline__ void bar() { asm volatile("s_barrier" ::: "memory"); }
#define VMCNT(n) asm volatile("s_waitcnt vmcnt(" #n ")" ::: "memory")

// ---------------- prep: grid-strided cvt + W transpose (R11) ----------------

__global__ __launch_bounds__(256) void k_prep(
    const float4* __restrict__ y4, const float4* __restrict__ a4,
    ushort4* __restrict__ yb, ushort4* __restrict__ ab,
    const float* __restrict__ W, unsigned short* __restrict__ Wt)
{
  const int bid = blockIdx.x;
  if (bid < 2048) {
    const bool isY = bid < 1024;
    const float4* __restrict__ src = isY ? y4 : a4;
    ushort4* __restrict__ dst = isY ? yb : ab;
    int idx = (bid & 1023) * 256 + (int)threadIdx.x;
#pragma unroll
    for (int it = 0; it < 8; ++it, idx += 262144) {
      const float4 v = src[idx];
      ushort4 p;
      p.x = f2bf(v.x); p.y = f2bf(v.y); p.z = f2bf(v.z); p.w = f2bf(v.w);
      dst[idx] = p;
    }
  } else {
    __shared__ float t[64][65];
    const int id = bid - 2048;
    const int n0 = (id & 15) * 64, k0 = (id >> 4) * 64;
    const int tx = threadIdx.x & 63, ty = threadIdx.x >> 6;
#pragma unroll
    for (int r = ty; r < 64; r += 4)
      t[r][tx] = W[(size_t)(k0 + r) * 1024 + n0 + tx];
    __syncthreads();
#pragma unroll
    for (int r = ty; r < 64; r += 4)
      Wt[(size_t)(n0 + r) * 1024 + k0 + tx] = f2bf(t[tx][r]);
  }
}

// ---------------- GEMM pieces: 256x128 tile, BK=64, 8 waves ----------------
// LDS buffer (48KB x3): A[256][64] bf16 at +0, B[128][64] at +16384 (ushort).
// Row = 128B = 8 chunks of 16B; physical chunk = (logical + row) & 7.
// gload_lds: linear dest + inverse-swizzled source k-column (proven R3+).
// Stage units: A-half c (16KB, 2 loads/thread), B-quarter u (8KB, 1 load):
//   B unit u covers rows {u*32 + (w&3)*8 + (w>>2)*64} = the rows phase u needs
//   (ph_alpha: nj 0-1 -> wn+0..31 for wn in {0,64}; ph_beta: +32).

__device__ __forceinline__ void stageA_u(
    const unsigned short* __restrict__ A, int sA, int m0, int k0, int c,
    unsigned short* la, int wave, int rg, int colo)
{
#pragma unroll
  for (int s = 0; s < 2; ++s) {
    const int t = wave * 2 + s;                        // 0..15
    const int row0 = (t >> 2) * 64 + c * 32 + (t & 3) * 8;
    async_cp16(A + (size_t)(m0 + row0 + rg) * sA + k0 + colo, la + row0 * 64);
  }
}

__device__ __forceinline__ void stageB_u(
    const unsigned short* __restrict__ Bt, int sB, int n0, int k0, int u,
    unsigned short* lb, int wave, int rg, int colo)
{
  const int row0 = u * 32 + (wave & 3) * 8 + (wave >> 2) * 64;
  async_cp16(Bt + (size_t)(n0 + row0 + rg) * sB + k0 + colo, lb + row0 * 64);
}

__device__ __forceinline__ void readA(
    const unsigned short* la, bf16x8 af[2][4], int wm, int quad, int l16)
{
#pragma unroll
  for (int h = 0; h < 2; ++h)
#pragma unroll
    for (int i = 0; i < 4; ++i) {
      const int r = wm + i * 16 + l16;
      af[h][i] = *(const bf16x8*)(la + r * 64 + ((h * 4 + quad + r) & 7) * 8);
    }
}

__device__ __forceinline__ void readBh(
    const unsigned short* lb, bf16x8 bfr[2][2], int wn, int half, int quad, int l16)
{
#pragma unroll
  for (int h = 0; h < 2; ++h)
#pragma unroll
    for (int j = 0; j < 2; ++j) {
      const int r = wn + half * 32 + j * 16 + l16;
      bfr[h][j] = *(const bf16x8*)(lb + r * 64 + ((h * 4 + quad + r) & 7) * 8);
    }
}

__device__ __forceinline__ void mfma16(
    bf16x8 af[2][4], bf16x8 bfr[2][2], f32x4 acc[4][4], int half)
{
  __builtin_amdgcn_s_setprio(1);
#pragma unroll
  for (int h = 0; h < 2; ++h)
#pragma unroll
    for (int i = 0; i < 4; ++i)
#pragma unroll
      for (int j = 0; j < 2; ++j)
        acc[i][half * 2 + j] = __builtin_amdgcn_mfma_f32_16x16x32_bf16(
            af[h][i], bfr[h][j], acc[i][half * 2 + j], 0, 0, 0);
  __builtin_amdgcn_s_setprio(0);
}

// 16 K-tiles, triple-buffered, staged 2 tiles ahead, 2 fine phases per tile.
// vmcnt ledger (steady): before ph_beta wait, outstanding = 6(T+1) + 6(T+2);
// vmcnt(6) drains T+1 exactly. WAR: stage target (T+2)%3 == (T-1)%3, whose
// last readers passed a barrier during iteration T-1.
__device__ __forceinline__ void gemm_fine(
    const unsigned short* __restrict__ A,  int sA,
    const unsigned short* __restrict__ Bt, int sB,
    int m0, int n0, f32x4 acc[4][4], unsigned short* lsm, int tid)
{
  const int lane = tid & 63, wave = tid >> 6;
  const int wm = (wave >> 1) * 64, wn = (wave & 1) * 64;
  const int quad = lane >> 4, l16 = lane & 15;
  const int rg = lane >> 3;
  const int colo = (((lane & 7) - rg) & 7) * 8;   // inverse-swizzled k-offset

  bf16x8 af[2][4], bfr[2][2];

  // prologue: stage tiles 0,1 fully (6 loads each); drain tile 0 only
  {
    unsigned short* b0 = lsm;
    unsigned short* b1 = lsm + 24576;
    stageA_u(A, sA, m0, 0, 0, b0, wave, rg, colo);
    stageA_u(A, sA, m0, 0, 1, b0, wave, rg, colo);
    stageB_u(Bt, sB, n0, 0, 0, b0 + 16384, wave, rg, colo);
    stageB_u(Bt, sB, n0, 0, 1, b0 + 16384, wave, rg, colo);
    stageA_u(A, sA, m0, 64, 0, b1, wave, rg, colo);
    stageA_u(A, sA, m0, 64, 1, b1, wave, rg, colo);
    stageB_u(Bt, sB, n0, 64, 0, b1 + 16384, wave, rg, colo);
    stageB_u(Bt, sB, n0, 64, 1, b1 + 16384, wave, rg, colo);
    VMCNT(6);
    bar();
  }

  int curi = 0, stgi = 2;
#pragma unroll 1
  for (int T = 0; T < 16; ++T) {
    const unsigned short* cur = lsm + curi * 24576;
    unsigned short* stg = lsm + stgi * 24576;
    const int nk = (T + 2) * 64;

    // ---- phase alpha: acc cols 0-1 ----
    if (T < 14) {
      stageA_u(A, sA, m0, nk, 0, stg, wave, rg, colo);
      stageB_u(Bt, sB, n0, nk, 0, stg + 16384, wave, rg, colo);
    }
    readA(cur, af, wm, quad, l16);
    readBh(cur + 16384, bfr, wn, 0, quad, l16);
    bar();
    mfma16(af, bfr, acc, 0);
    bar();

    // ---- phase beta: acc cols 2-3 ----
    if (T < 14) {
      stageA_u(A, sA, m0, nk, 1, stg, wave, rg, colo);
      stageB_u(Bt, sB, n0, nk, 1, stg + 16384, wave, rg, colo);
    }
    readA(cur, af, wm, quad, l16);
    readBh(cur + 16384, bfr, wn, 1, quad, l16);
    if (T < 14)       { VMCNT(6); }
    else if (T == 14) { VMCNT(0); }
    bar();
    mfma16(af, bfr, acc, 1);
    bar();

    curi = (curi + 1) == 3 ? 0 : curi + 1;
    stgi = (stgi + 1) == 3 ? 0 : stgi + 1;
  }
}

__device__ __forceinline__ void zero_acc(f32x4 acc[4][4]) {
#pragma unroll
  for (int i = 0; i < 4; ++i)
#pragma unroll
    for (int j = 0; j < 4; ++j)
#pragma unroll
      for (int r = 0; r < 4; ++r) acc[i][j][r] = 0.0f;
}

// ---------------- GEMM1: Sup2[d][b*1024+n] = (y@W)^T ----------------
// 256 blocks; xcd = bid&7 owns 8 consecutive n-tiles -> per-XCD working set
// Wt (2MB) + ybf n-slice (2MB) = one L2.

__global__ __launch_bounds__(512, 2) void k_gemm1(
    const unsigned short* __restrict__ Wt,    // [1024][1024]
    const unsigned short* __restrict__ Ybf,   // [8192][1024]
    unsigned short* __restrict__ Sup2)        // [1024][8192]
{
  __shared__ __align__(16) unsigned short lsm[73728];  // 144 KB
  const int tid = threadIdx.x;
  const int xcd = blockIdx.x & 7, slot = blockIdx.x >> 3;  // slot 0..31
  const int m0 = (slot >> 3) * 256;                        // 4 m-tiles
  const int n0 = (xcd * 8 + (slot & 7)) * 128;             // 64 n-tiles

  f32x4 acc[4][4];
  zero_acc(acc);
  gemm_fine(Wt, 1024, Ybf, 1024, m0, n0, acc, lsm, tid);

  const int lane = tid & 63, wave = tid >> 6;
  const int wm = (wave >> 1) * 64, wn = (wave & 1) * 64;
  const int quad = lane >> 4, l16 = lane & 15;
#pragma unroll
  for (int mi = 0; mi < 4; ++mi) {
    const int mb = m0 + wm + mi * 16 + quad * 4;
#pragma unroll
    for (int r = 0; r < 4; ++r) {
      unsigned short* row = Sup2 + ((size_t)(mb + r) << 13);
#pragma unroll
      for (int nj = 0; nj < 4; ++nj)
        row[n0 + wn + nj * 16 + l16] = f2bf(acc[mi][nj][r]);
    }
  }
}

// ------- GEMM2: out = relu(adj@support / rowsum + bias + x) -------
// 256 blocks; xcd = bid&7 owns batch b -> adjbf[b] (2MB) + sup2 b-slice (2MB)
// = one L2.

__global__ __launch_bounds__(512, 2) void k_gemm2(
    const unsigned short* __restrict__ AdjBf, // [8][1024][1024]
    const unsigned short* __restrict__ Sup2,  // [1024][8192]
    const float* __restrict__ x,
    const float* __restrict__ sumrow,         // [8][1024]
    const float* __restrict__ bias,           // [1024]
    float* __restrict__ out)
{
  __shared__ __align__(16) unsigned short lsm[73728];  // 144 KB
  const int tid = threadIdx.x;
  const int b = blockIdx.x & 7, slot = blockIdx.x >> 3;  // slot 0..31
  const int m0 = (slot >> 3) * 256, n0 = (slot & 7) * 128;

  f32x4 acc[4][4];
  zero_acc(acc);
  gemm_fine(AdjBf + ((size_t)b << 20), 1024,
            Sup2 + ((size_t)b << 10), 8192,
            m0, n0, acc, lsm, tid);

  const float* xb = x   + ((size_t)b << 20);
  float*       ob = out + ((size_t)b << 20);
  const float* sr = sumrow + ((size_t)b << 10);
  const int lane = tid & 63, wave = tid >> 6;
  const int wm = (wave >> 1) * 64, wn = (wave & 1) * 64;
  const int quad = lane >> 4, l16 = lane & 15;

  float bv[4];
#pragma unroll
  for (int nj = 0; nj < 4; ++nj) bv[nj] = bias[n0 + wn + nj * 16 + l16];

#pragma unroll
  for (int mi = 0; mi < 4; ++mi) {
    const int mb = m0 + wm + mi * 16 + quad * 4;
#pragma unroll
    for (int r = 0; r < 4; ++r) {
      const int m = mb + r;
      const float inv = 1.0f / sr[m];
#pragma unroll
      for (int nj = 0; nj < 4; ++nj) {
        const int n = n0 + wn + nj * 16 + l16;
        const size_t idx = (((size_t)m) << 10) + n;
        float v = acc[mi][nj][r] * inv + bv[nj] + xb[idx];
        ob[idx] = fmaxf(v, 0.0f);
      }
    }
  }
}

// ---------------- launcher ----------------

extern "C" void kernel_launch(void* const* d_in, const int* in_sizes, int n_in,
                              void* d_out, int out_size, void* d_ws, size_t ws_size,
                              hipStream_t stream) {
  const float* x      = (const float*)d_in[0];
  const float* y      = (const float*)d_in[1];
  const float* adj    = (const float*)d_in[2];
  const float* sumrow = (const float*)d_in[3];
  const float* W      = (const float*)d_in[4];
  const float* bias   = (const float*)d_in[5];
  float* out = (float*)d_out;

  char* ws = (char*)d_ws;
  unsigned short* ybf   = (unsigned short*)(ws);                       // 16 MB
  unsigned short* adjbf = (unsigned short*)(ws + ((size_t)16 << 20));  // 16 MB
  unsigned short* wt    = (unsigned short*)(ws + ((size_t)32 << 20));  //  2 MB
  unsigned short* sup2  = (unsigned short*)(ws + ((size_t)34 << 20));  // 16 MB

  k_prep<<<dim3(2304), dim3(256), 0, stream>>>(
      (const float4*)y, (const float4*)adj, (ushort4*)ybf, (ushort4*)adjbf, W, wt);
  k_gemm1<<<dim3(256), dim3(512), 0, stream>>>(wt, ybf, sup2);
  k_gemm2<<<dim3(256), dim3(512), 0, stream>>>(adjbf, sup2, x, sumrow, bias, out);
}

// Round 11
// 192.791 us; speedup vs baseline: 1.0558x; 1.0558x over previous
//
#include <hip/hip_runtime.h>
#include <hip/hip_bf16.h>
#include <stdint.h>

// B=8, N=1024, D=1024.  out = relu(adj @ (y@W) / adj_sumrow + b + x)
// R14: producer-wave overlap (m114: separate waves co-schedule at max, not
// sum). k_gemm1 = 768 thr: waves 0-7 run the R8 gemm verbatim; waves 8-11
// stream adj f32->bf16 (32 float4/thread, reg-pipelined), matching the gemm
// path's 32 s_barriers exactly. Prep shrinks to y+W. R12 proved same-wave
// folding conserves time; this puts conversion in DIFFERENT waves.
// gemm2 = R8 verbatim. K-loop itself is schedule-invariant (R3-R13 sweep).

typedef float  f32x4  __attribute__((ext_vector_type(4)));
typedef __bf16 bf16x8 __attribute__((ext_vector_type(8)));

__device__ __forceinline__ unsigned short f2bf(float f) {
  union { float f; unsigned int u; } c; c.f = f;
  unsigned int u = c.u;
  u += 0x7FFFu + ((u >> 16) & 1u);   // RNE; inputs finite
  return (unsigned short)(u >> 16);
}

__device__ __forceinline__ void async_cp16(const void* g, void* l) {
  __builtin_amdgcn_global_load_lds(
      (const __attribute__((address_space(1))) unsigned int*)g,
      (__attribute__((address_space(3))) unsigned int*)l, 16, 0, 0);
}

__device__ __forceinline__ void bar() { asm volatile("s_barrier" ::: "memory"); }
#define VMCNT(n) asm volatile("s_waitcnt vmcnt(" #n ")" ::: "memory")

// ---------------- prep: y cvt (grid-stride) + W transpose ----------------

__global__ __launch_bounds__(256) void k_prep(
    const float4* __restrict__ y4, ushort4* __restrict__ yb,
    const float* __restrict__ W, unsigned short* __restrict__ Wt)
{
  const int bid = blockIdx.x;
  if (bid < 1024) {
    int idx = bid * 256 + (int)threadIdx.x;
#pragma unroll
    for (int it = 0; it < 8; ++it, idx += 262144) {
      const float4 v = y4[idx];
      ushort4 p;
      p.x = f2bf(v.x); p.y = f2bf(v.y); p.z = f2bf(v.z); p.w = f2bf(v.w);
      yb[idx] = p;
    }
  } else {
    __shared__ float t[64][65];
    const int id = bid - 1024;
    const int n0 = (id & 15) * 64, k0 = (id >> 4) * 64;
    const int tx = threadIdx.x & 63, ty = threadIdx.x >> 6;
#pragma unroll
    for (int r = ty; r < 64; r += 4)
      t[r][tx] = W[(size_t)(k0 + r) * 1024 + n0 + tx];
    __syncthreads();
#pragma unroll
    for (int r = ty; r < 64; r += 4)
      Wt[(size_t)(n0 + r) * 1024 + k0 + tx] = f2bf(t[tx][r]);
  }
}

// ---------------- GEMM pieces: 256x128 tile, BK=64, 8 waves (R8) ----------
// LDS row = 128B = 8 chunks of 16B; physical chunk = (logical + row) & 7.
// Staging applies the inverse permutation on the global k-column; all staging
// row bases are multiples of 8 so the mod-8 algebra is unchanged (proven R3+).

__device__ __forceinline__ void stageA(
    const unsigned short* __restrict__ A, int sA, int m0, int k0, int c,
    unsigned short* la, int wave, int rg, int colo)
{
#pragma unroll
  for (int s = 0; s < 2; ++s) {
    const int t = wave * 2 + s;                        // 0..15
    const int row0 = (t >> 2) * 64 + c * 32 + (t & 3) * 8;
    async_cp16(A + (size_t)(m0 + row0 + rg) * sA + k0 + colo, la + row0 * 64);
  }
}

__device__ __forceinline__ void stageB(
    const unsigned short* __restrict__ Bt, int sB, int n0, int k0,
    unsigned short* lb, int wave, int rg, int colo)
{
#pragma unroll
  for (int s = 0; s < 2; ++s) {
    const int t = wave * 2 + s;                        // 0..15
    const int row0 = t * 8;
    async_cp16(Bt + (size_t)(n0 + row0 + rg) * sB + k0 + colo, lb + row0 * 64);
  }
}

__device__ __forceinline__ void readA(
    const unsigned short* la, bf16x8 af[2][2], int wm, int mh, int quad, int l16)
{
#pragma unroll
  for (int h = 0; h < 2; ++h)
#pragma unroll
    for (int i = 0; i < 2; ++i) {
      const int r = wm + mh * 32 + i * 16 + l16;
      af[h][i] = *(const bf16x8*)(la + r * 64 + ((h * 4 + quad + r) & 7) * 8);
    }
}

__device__ __forceinline__ void readB(
    const unsigned short* lb, bf16x8 bfr[2][2], int wn, int nh, int quad, int l16)
{
#pragma unroll
  for (int h = 0; h < 2; ++h)
#pragma unroll
    for (int j = 0; j < 2; ++j) {
      const int r = wn + nh * 32 + j * 16 + l16;
      bfr[h][j] = *(const bf16x8*)(lb + r * 64 + ((h * 4 + quad + r) & 7) * 8);
    }
}

__device__ __forceinline__ void quad8(
    bf16x8 af[2][2], bf16x8 bfr[2][2], f32x4 acc[4][4], int mh, int nh)
{
  __builtin_amdgcn_s_setprio(1);
#pragma unroll
  for (int h = 0; h < 2; ++h)
#pragma unroll
    for (int i = 0; i < 2; ++i)
#pragma unroll
      for (int j = 0; j < 2; ++j)
        acc[mh * 2 + i][nh * 2 + j] = __builtin_amdgcn_mfma_f32_16x16x32_bf16(
            af[h][i], bfr[h][j], acc[mh * 2 + i][nh * 2 + j], 0, 0, 0);
  __builtin_amdgcn_s_setprio(0);
}

// R8 K-loop. Barrier count: 15 iters x 2 + tail 2 = 32 (uniform, no bars
// after the last common one) — conv waves must match exactly 32.
__device__ __forceinline__ void gemm256x128(
    const unsigned short* __restrict__ A,  int sA,
    const unsigned short* __restrict__ Bt, int sB,
    int m0, int n0, f32x4 acc[4][4], unsigned short* lsm, int tid)
{
  const int lane = tid & 63, wave = tid >> 6;
  const int wm = (wave >> 1) * 64, wn = (wave & 1) * 64;
  const int quad = lane >> 4, l16 = lane & 15;
  const int rg = lane >> 3;
  const int colo = (((lane & 7) - rg) & 7) * 8;

  bf16x8 af[2][2], bfr[2][2];

  stageA(A, sA, m0, 0, 0, lsm, wave, rg, colo);
  stageB(Bt, sB, n0, 0, lsm + 16384, wave, rg, colo);
  stageA(A, sA, m0, 0, 1, lsm, wave, rg, colo);

#pragma unroll 1
  for (int T = 0; T < 15; ++T) {
    const unsigned short* la = lsm + (T & 1) * 24576;
    const unsigned short* lb = la + 16384;
    unsigned short* na = lsm + ((T + 1) & 1) * 24576;
    unsigned short* nb = na + 16384;
    const int nk = (T + 1) * 64;

    stageA(A, sA, m0, nk, 0, na, wave, rg, colo);
    VMCNT(4); bar();
    readA(la, af, wm, 0, quad, l16);
    readB(lb, bfr, wn, 0, quad, l16);
    quad8(af, bfr, acc, 0, 0);

    stageB(Bt, sB, n0, nk, nb, wave, rg, colo);
    readB(lb, bfr, wn, 1, quad, l16);
    quad8(af, bfr, acc, 0, 1);

    stageA(A, sA, m0, nk, 1, na, wave, rg, colo);
    VMCNT(6); bar();
    readA(la, af, wm, 1, quad, l16);
    quad8(af, bfr, acc, 1, 1);

    readB(lb, bfr, wn, 0, quad, l16);
    quad8(af, bfr, acc, 1, 0);
  }
  {
    const unsigned short* la = lsm + 24576;
    const unsigned short* lb = la + 16384;
    VMCNT(2); bar();
    readA(la, af, wm, 0, quad, l16);
    readB(lb, bfr, wn, 0, quad, l16);
    quad8(af, bfr, acc, 0, 0);
    readB(lb, bfr, wn, 1, quad, l16);
    quad8(af, bfr, acc, 0, 1);
    VMCNT(0); bar();
    readA(la, af, wm, 1, quad, l16);
    quad8(af, bfr, acc, 1, 1);
    readB(lb, bfr, wn, 0, quad, l16);
    quad8(af, bfr, acc, 1, 0);
  }
}

__device__ __forceinline__ void zero_acc(f32x4 acc[4][4]) {
#pragma unroll
  for (int i = 0; i < 4; ++i)
#pragma unroll
    for (int j = 0; j < 4; ++j)
#pragma unroll
      for (int r = 0; r < 4; ++r) acc[i][j][r] = 0.0f;
}

// ---------------- GEMM1 (768 thr) + adj-conv producer waves ----------------
// waves 0-7: R8 gemm (Wt x Ybf -> Sup2). waves 8-11: adj f32->bf16, 32
// float4/thread reg-pipelined, 32 bar() calls matching the gemm path.
// 256 blocks; xcd = bid&7 owns 8 consecutive n-tiles (Wt 2MB + ybf 2MB /L2).

__global__ __launch_bounds__(768) void k_gemm1(
    const unsigned short* __restrict__ Wt,    // [1024][1024]
    const unsigned short* __restrict__ Ybf,   // [8192][1024]
    unsigned short* __restrict__ Sup2,        // [1024][8192]
    const float4* __restrict__ AdjF,          // adj as float4[2M]
    ushort4* __restrict__ AdjBf)              // adj bf16 out
{
  __shared__ __align__(16) unsigned short lsm[49152];  // 96 KB -> 1 blk/CU
  const int tid = threadIdx.x;

  if (tid < 512) {
    // ---------------- gemm role (R8 verbatim) ----------------
    const int xcd = blockIdx.x & 7, slot = blockIdx.x >> 3;  // slot 0..31
    const int m0 = (slot >> 3) * 256;
    const int n0 = (xcd * 8 + (slot & 7)) * 128;

    f32x4 acc[4][4];
    zero_acc(acc);
    gemm256x128(Wt, 1024, Ybf, 1024, m0, n0, acc, lsm, tid);

    const int lane = tid & 63, wave = tid >> 6;
    const int wm = (wave >> 1) * 64, wn = (wave & 1) * 64;
    const int quad = lane >> 4, l16 = lane & 15;
#pragma unroll
    for (int mi = 0; mi < 4; ++mi) {
      const int mb = m0 + wm + mi * 16 + quad * 4;
#pragma unroll
      for (int r = 0; r < 4; ++r) {
        unsigned short* row = Sup2 + ((size_t)(mb + r) << 13);
#pragma unroll
        for (int nj = 0; nj < 4; ++nj)
          row[n0 + wn + nj * 16 + l16] = f2bf(acc[mi][nj][r]);
      }
    }
  } else {
    // ---------------- conv role: 4 waves, 32 float4/thread ----------------
    const int ct = blockIdx.x * 256 + (tid - 512);   // 0..65535
    float4 cur = AdjF[ct];
#pragma unroll 1
    for (int it = 0; it < 32; ++it) {
      float4 nxt = cur;
      if (it < 31) nxt = AdjF[ct + (it + 1) * 65536];
      ushort4 p;
      p.x = f2bf(cur.x); p.y = f2bf(cur.y); p.z = f2bf(cur.z); p.w = f2bf(cur.w);
      AdjBf[ct + it * 65536] = p;
      cur = nxt;
      bar();                                          // match gemm bar #it+1
    }
    // gemm path has no barriers after its 32nd -> safe to exit here
  }
}

// ------- GEMM2: out = relu(adj@support / rowsum + bias + x) — R8 verbatim --
// 256 blocks; xcd = bid&7 owns batch b -> adjbf[b] (2MB) + sup2 b-slice (2MB).

__global__ __launch_bounds__(512, 2) void k_gemm2(
    const unsigned short* __restrict__ AdjBf, // [8][1024][1024]
    const unsigned short* __restrict__ Sup2,  // [1024][8192]
    const float* __restrict__ x,
    const float* __restrict__ sumrow,         // [8][1024]
    const float* __restrict__ bias,           // [1024]
    float* __restrict__ out)
{
  __shared__ __align__(16) unsigned short lsm[49152];  // 96 KB
  const int tid = threadIdx.x;
  const int b = blockIdx.x & 7, slot = blockIdx.x >> 3;  // slot 0..31
  const int m0 = (slot >> 3) * 256, n0 = (slot & 7) * 128;

  f32x4 acc[4][4];
  zero_acc(acc);
  gemm256x128(AdjBf + ((size_t)b << 20), 1024,
              Sup2 + ((size_t)b << 10), 8192,
              m0, n0, acc, lsm, tid);

  const float* xb = x   + ((size_t)b << 20);
  float*       ob = out + ((size_t)b << 20);
  const float* sr = sumrow + ((size_t)b << 10);
  const int lane = tid & 63, wave = tid >> 6;
  const int wm = (wave >> 1) * 64, wn = (wave & 1) * 64;
  const int quad = lane >> 4, l16 = lane & 15;

  float bv[4];
#pragma unroll
  for (int nj = 0; nj < 4; ++nj) bv[nj] = bias[n0 + wn + nj * 16 + l16];

#pragma unroll
  for (int mi = 0; mi < 4; ++mi) {
    const int mb = m0 + wm + mi * 16 + quad * 4;
#pragma unroll
    for (int r = 0; r < 4; ++r) {
      const int m = mb + r;
      const float inv = 1.0f / sr[m];
#pragma unroll
      for (int nj = 0; nj < 4; ++nj) {
        const int n = n0 + wn + nj * 16 + l16;
        const size_t idx = (((size_t)m) << 10) + n;
        float v = acc[mi][nj][r] * inv + bv[nj] + xb[idx];
        ob[idx] = fmaxf(v, 0.0f);
      }
    }
  }
}

// ---------------- launcher ----------------

extern "C" void kernel_launch(void* const* d_in, const int* in_sizes, int n_in,
                              void* d_out, int out_size, void* d_ws, size_t ws_size,
                              hipStream_t stream) {
  const float* x      = (const float*)d_in[0];
  const float* y      = (const float*)d_in[1];
  const float* adj    = (const float*)d_in[2];
  const float* sumrow = (const float*)d_in[3];
  const float* W      = (const float*)d_in[4];
  const float* bias   = (const float*)d_in[5];
  float* out = (float*)d_out;

  char* ws = (char*)d_ws;
  unsigned short* ybf   = (unsigned short*)(ws);                       // 16 MB
  unsigned short* adjbf = (unsigned short*)(ws + ((size_t)16 << 20));  // 16 MB
  unsigned short* wt    = (unsigned short*)(ws + ((size_t)32 << 20));  //  2 MB
  unsigned short* sup2  = (unsigned short*)(ws + ((size_t)34 << 20));  // 16 MB

  k_prep<<<dim3(1280), dim3(256), 0, stream>>>(
      (const float4*)y, (ushort4*)ybf, W, wt);
  k_gemm1<<<dim3(256), dim3(768), 0, stream>>>(
      wt, ybf, sup2, (const float4*)adj, (ushort4*)adjbf);
  k_gemm2<<<dim3(256), dim3(512), 0, stream>>>(adjbf, sup2, x, sumrow, bias, out);
}